// Round 1
// 4092.403 us; speedup vs baseline: 1.3675x; 1.3675x over previous
//
#include <hip/hip_runtime.h>
#include <hip/hip_bf16.h>
#include <math.h>

// GPT-2 small, 4 layers: V=50257, T=1024, D=768, F=3072, H=12, HD=64, B=2.
// Round 1: LM-head GEMM moved to bf16 MFMA (split-bf16 hi/lo, 3-term products
// for ~fp32 accuracy). m97-style structure: 128x128 tile, BK=32,
// global_load_lds width=16, 2-barrier K-loop, 16x16x32 bf16 MFMA.
// Workspace (fp32): X | H | QKV | U  = 56.6 MB, then
//   Ahi/Alo bf16 [2048*768] (6.3 MB) | W chunk hi/lo bf16 (ws-size dependent).

constexpr int kB  = 2;
constexpr int kT  = 1024;
constexpr int kD  = 768;
constexpr int kF  = 3072;
constexpr int kH  = 12;
constexpr int kHD = 64;
constexpr int kL  = 4;
constexpr int kV  = 50257;
constexpr int kM  = kB * kT;   // 2048 rows
constexpr int kVpad = 50304;   // 393 * 128

typedef __attribute__((ext_vector_type(8))) short bf16x8;
typedef __attribute__((ext_vector_type(4))) float f32x4;

#define GLDS16(g, l)                                                         \
  __builtin_amdgcn_global_load_lds(                                          \
      (const __attribute__((address_space(1))) void*)(g),                    \
      (__attribute__((address_space(3))) void*)(l), 16, 0, 0)

// ---------------------------------------------------------------- embed ----
__global__ __launch_bounds__(256)
void k_embed(const int* __restrict__ tok, const float* __restrict__ wte,
             const float* __restrict__ wpe, float* __restrict__ x) {
  int idx = blockIdx.x * 256 + threadIdx.x;        // float4 index
  int row = idx / (kD / 4);
  int c4  = idx % (kD / 4);
  int t   = row % kT;
  int token = tok[row];
  float4 a = ((const float4*)wte)[(size_t)token * (kD / 4) + c4];
  float4 b = ((const float4*)wpe)[(size_t)t * (kD / 4) + c4];
  float4 o; o.x = a.x + b.x; o.y = a.y + b.y; o.z = a.z + b.z; o.w = a.w + b.w;
  ((float4*)x)[idx] = o;
}

// ------------------------------------------------------------ layernorm ----
// one wave per row (D=768 = 12 elems/lane), block = 4 waves.
__global__ __launch_bounds__(256)
void k_ln(const float* __restrict__ x, const float* __restrict__ w,
          const float* __restrict__ b, float* __restrict__ out) {
  int wave = threadIdx.x >> 6, lane = threadIdx.x & 63;
  int row = blockIdx.x * 4 + wave;
  const float* xr = x + (size_t)row * kD;
  float v[12];
  float s = 0.f;
#pragma unroll
  for (int i = 0; i < 12; i++) { v[i] = xr[lane + i * 64]; s += v[i]; }
#pragma unroll
  for (int off = 32; off >= 1; off >>= 1) s += __shfl_xor(s, off, 64);
  float mu = s * (1.f / kD);
  float q = 0.f;
#pragma unroll
  for (int i = 0; i < 12; i++) { float d = v[i] - mu; q += d * d; }
#pragma unroll
  for (int off = 32; off >= 1; off >>= 1) q += __shfl_xor(q, off, 64);
  float rs = rsqrtf(q * (1.f / kD) + 1e-5f);
  float* orow = out + (size_t)row * kD;
#pragma unroll
  for (int i = 0; i < 12; i++) {
    int c = lane + i * 64;
    orow[c] = (v[i] - mu) * rs * w[c] + b[c];
  }
}

// ----------------------------------------------------------------- gelu ----
__device__ __forceinline__ float gelu_f(float x) {
  const float c = 0.7978845608028654f;  // sqrt(2/pi)
  float x3 = x * x * x;
  return 0.5f * x * (1.f + tanhf(c * (x + 0.044715f * x3)));
}

// ----------------------------------------------------------------- GEMM ----
// C[M,N] = act(A[M,K] @ W[K,N] + bias) (+ res). BM=BN=64, BK=16,
// 256 threads, 4x4 micro-tile per thread. ACT: 0=none, 1=GELU.
template <int ACT>
__global__ __launch_bounds__(256)
void k_gemm(const float* __restrict__ A, const float* __restrict__ W,
            const float* __restrict__ bias, const float* __restrict__ res,
            float* __restrict__ C, int M, int N, int K) {
  __shared__ float As[16][64];   // As[k][m]
  __shared__ float Ws[16][64];   // Ws[k][n]
  int tid = threadIdx.x;
  int bm = blockIdx.y * 64, bn = blockIdx.x * 64;
  int tx = tid & 15, ty = tid >> 4;          // C tile coords
  int arow = tid >> 2, ak = (tid & 3) * 4;   // A staging
  int wk = tid >> 4, wn = (tid & 15) * 4;    // W staging
  const float* Aptr = A + (size_t)(bm + arow) * K + ak;
  const float* Wptr = W + (size_t)wk * N + bn + wn;
  float acc[4][4] = {};
  for (int k0 = 0; k0 < K; k0 += 16) {
    float4 av = *(const float4*)(Aptr + k0);
    float4 wv = *(const float4*)(Wptr + (size_t)k0 * N);
    __syncthreads();
    As[ak + 0][arow] = av.x; As[ak + 1][arow] = av.y;
    As[ak + 2][arow] = av.z; As[ak + 3][arow] = av.w;
    *(float4*)&Ws[wk][wn] = wv;
    __syncthreads();
#pragma unroll
    for (int kk = 0; kk < 16; kk++) {
      float4 a4 = *(const float4*)&As[kk][ty * 4];
      float4 w4 = *(const float4*)&Ws[kk][tx * 4];
      float am[4] = {a4.x, a4.y, a4.z, a4.w};
      float wm[4] = {w4.x, w4.y, w4.z, w4.w};
#pragma unroll
      for (int i = 0; i < 4; i++)
#pragma unroll
        for (int j = 0; j < 4; j++)
          acc[i][j] = fmaf(am[i], wm[j], acc[i][j]);
    }
  }
  float4 bv = *(const float4*)(bias + bn + tx * 4);
  float bm4[4] = {bv.x, bv.y, bv.z, bv.w};
#pragma unroll
  for (int i = 0; i < 4; i++) {
    int m = bm + ty * 4 + i;
    size_t base = (size_t)m * N + bn + tx * 4;
    float o[4];
#pragma unroll
    for (int j = 0; j < 4; j++) {
      float v = acc[i][j] + bm4[j];
      if (ACT == 1) v = gelu_f(v);
      o[j] = v;
    }
    if (res) {
      float4 rv = *(const float4*)(res + base);
      o[0] += rv.x; o[1] += rv.y; o[2] += rv.z; o[3] += rv.w;
    }
    float4 ov; ov.x = o[0]; ov.y = o[1]; ov.z = o[2]; ov.w = o[3];
    *(float4*)(C + base) = ov;
  }
}

// ---------------------------------------------- head GEMM fallback (fp32) --
__global__ __launch_bounds__(256)
void k_gemm_bt(const float* __restrict__ A, const float* __restrict__ Wt,
               float* __restrict__ C, int M, int N, int K) {
  __shared__ float As[16][64];
  __shared__ float Ws[16][64];
  int tid = threadIdx.x;
  int bm = blockIdx.y * 64, bn = blockIdx.x * 64;
  int tx = tid & 15, ty = tid >> 4;
  int arow = tid >> 2, ak = (tid & 3) * 4;
  int nloc = tid >> 2, nk = (tid & 3) * 4;
  int ng = bn + nloc;
  const float* Aptr = A + (size_t)(bm + arow) * K + ak;
  const float* Wptr = Wt + (size_t)ng * K + nk;
  bool wok = (ng < N);
  float acc[4][4] = {};
  for (int k0 = 0; k0 < K; k0 += 16) {
    float4 av = *(const float4*)(Aptr + k0);
    float4 wv = make_float4(0.f, 0.f, 0.f, 0.f);
    if (wok) wv = *(const float4*)(Wptr + k0);
    __syncthreads();
    As[ak + 0][arow] = av.x; As[ak + 1][arow] = av.y;
    As[ak + 2][arow] = av.z; As[ak + 3][arow] = av.w;
    Ws[nk + 0][nloc] = wv.x; Ws[nk + 1][nloc] = wv.y;
    Ws[nk + 2][nloc] = wv.z; Ws[nk + 3][nloc] = wv.w;
    __syncthreads();
#pragma unroll
    for (int kk = 0; kk < 16; kk++) {
      float4 a4 = *(const float4*)&As[kk][ty * 4];
      float4 w4 = *(const float4*)&Ws[kk][tx * 4];
      float am[4] = {a4.x, a4.y, a4.z, a4.w};
      float wm[4] = {w4.x, w4.y, w4.z, w4.w};
#pragma unroll
      for (int i = 0; i < 4; i++)
#pragma unroll
        for (int j = 0; j < 4; j++)
          acc[i][j] = fmaf(am[i], wm[j], acc[i][j]);
    }
  }
#pragma unroll
  for (int i = 0; i < 4; i++) {
    int m = bm + ty * 4 + i;
#pragma unroll
    for (int j = 0; j < 4; j++) {
      int n = bn + tx * 4 + j;
      if (n < N) C[(size_t)m * N + n] = acc[i][j];
    }
  }
}

// -------------------------------------------------- split-bf16 cast utils --
__device__ __forceinline__ unsigned short bf_rne(float x) {
  unsigned u = __float_as_uint(x);
  unsigned r = (u + 0x7fffu + ((u >> 16) & 1u)) >> 16;
  return (unsigned short)r;
}

// cast activations [kM, kD] fp32 -> hi/lo bf16
__global__ __launch_bounds__(256)
void k_castA(const float* __restrict__ in, unsigned short* __restrict__ hi,
             unsigned short* __restrict__ lo) {
  int idx = blockIdx.x * 256 + threadIdx.x;   // float4 index
  float4 v = ((const float4*)in)[idx];
  float f[4] = {v.x, v.y, v.z, v.w};
  unsigned short hh[4], ll[4];
#pragma unroll
  for (int i = 0; i < 4; i++) {
    hh[i] = bf_rne(f[i]);
    float hf = __uint_as_float((unsigned)hh[i] << 16);
    ll[i] = bf_rne(f[i] - hf);
  }
  ushort4 h; h.x = hh[0]; h.y = hh[1]; h.z = hh[2]; h.w = hh[3];
  ushort4 l; l.x = ll[0]; l.y = ll[1]; l.z = ll[2]; l.w = ll[3];
  ((ushort4*)hi)[idx] = h;
  ((ushort4*)lo)[idx] = l;
}

// cast head_w rows [n0, n0+rc) fp32 -> hi/lo bf16 chunk buffer (zero-pad >= V)
__global__ __launch_bounds__(256)
void k_castW(const float* __restrict__ w, unsigned short* __restrict__ hi,
             unsigned short* __restrict__ lo, int n0) {
  int idx = blockIdx.x * 256 + threadIdx.x;   // float4 index within chunk
  int r  = idx / (kD / 4);
  int c4 = idx % (kD / 4);
  int n = n0 + r;
  float4 v = make_float4(0.f, 0.f, 0.f, 0.f);
  if (n < kV) v = ((const float4*)(w + (size_t)n * kD))[c4];
  float f[4] = {v.x, v.y, v.z, v.w};
  unsigned short hh[4], ll[4];
#pragma unroll
  for (int i = 0; i < 4; i++) {
    hh[i] = bf_rne(f[i]);
    float hf = __uint_as_float((unsigned)hh[i] << 16);
    ll[i] = bf_rne(f[i] - hf);
  }
  ushort4 h; h.x = hh[0]; h.y = hh[1]; h.z = hh[2]; h.w = hh[3];
  ushort4 l; l.x = ll[0]; l.y = ll[1]; l.z = ll[2]; l.w = ll[3];
  ((ushort4*)hi)[idx] = h;
  ((ushort4*)lo)[idx] = l;
}

// --------------------------------------------- head GEMM, bf16 MFMA split --
// C[m, n0+n] = sum_k A[m,k] * W[n,k],  A,W given as hi/lo bf16 pairs.
// Tile 128x128, BK=32, 256 threads = 4 waves (2x2), each wave 64x64 =
// 4x4 fragments of 16x16; mfma_f32_16x16x32_bf16, 3 MFMAs per frag pair.
__global__ __launch_bounds__(256)
void k_head_mfma(const unsigned short* __restrict__ Ahi,
                 const unsigned short* __restrict__ Alo,
                 const unsigned short* __restrict__ Whi,
                 const unsigned short* __restrict__ Wlo,
                 float* __restrict__ C, int n0) {
  __shared__ unsigned short As_hi[128 * 32];   // [row][k], 64 B rows, 8 KB
  __shared__ unsigned short As_lo[128 * 32];
  __shared__ unsigned short Bs_hi[128 * 32];
  __shared__ unsigned short Bs_lo[128 * 32];
  int tid = threadIdx.x;
  int lane = tid & 63, wave = tid >> 6;
  int wm = wave >> 1, wn = wave & 1;
  int bm  = blockIdx.x * 128;        // M fastest-varying: B panel L2 reuse
  int bnl = blockIdx.y * 128;        // local col within chunk

  // staging: thread covers (row = tid>>2 [+64 on round 1], k-quad = tid&3)
  int ar0 = tid >> 2;
  int akq = (tid & 3) * 8;           // bf16 elements
  const unsigned short* gAh = Ahi + (size_t)(bm + ar0) * kD + akq;
  const unsigned short* gAl = Alo + (size_t)(bm + ar0) * kD + akq;
  const unsigned short* gBh = Whi + (size_t)(bnl + ar0) * kD + akq;
  const unsigned short* gBl = Wlo + (size_t)(bnl + ar0) * kD + akq;
  unsigned ldsoff = (unsigned)(wave * 64) * 16;   // wave-uniform byte base
  const size_t gstep = (size_t)64 * kD;           // +64 rows for round 1

  f32x4 acc[4][4];
#pragma unroll
  for (int i = 0; i < 4; i++)
#pragma unroll
    for (int j = 0; j < 4; j++) acc[i][j] = (f32x4){0.f, 0.f, 0.f, 0.f};

  int fr = lane & 15;                 // row within 16x16 fragment
  int kh = (lane >> 4) * 8;           // k element offset within BK=32

  for (int k0 = 0; k0 < kD; k0 += 32) {
    __syncthreads();                  // previous compute done (drains lgkm)
    GLDS16(gAh + k0,         (char*)As_hi + ldsoff);
    GLDS16(gAh + k0 + gstep, (char*)As_hi + ldsoff + 4096);
    GLDS16(gAl + k0,         (char*)As_lo + ldsoff);
    GLDS16(gAl + k0 + gstep, (char*)As_lo + ldsoff + 4096);
    GLDS16(gBh + k0,         (char*)Bs_hi + ldsoff);
    GLDS16(gBh + k0 + gstep, (char*)Bs_hi + ldsoff + 4096);
    GLDS16(gBl + k0,         (char*)Bs_lo + ldsoff);
    GLDS16(gBl + k0 + gstep, (char*)Bs_lo + ldsoff + 4096);
    __syncthreads();                  // drains vmcnt(0): tiles ready

    bf16x8 ah[4], al[4], bh[4], bl[4];
#pragma unroll
    for (int i = 0; i < 4; i++) {
      ah[i] = *(const bf16x8*)&As_hi[(wm * 64 + i * 16 + fr) * 32 + kh];
      al[i] = *(const bf16x8*)&As_lo[(wm * 64 + i * 16 + fr) * 32 + kh];
      bh[i] = *(const bf16x8*)&Bs_hi[(wn * 64 + i * 16 + fr) * 32 + kh];
      bl[i] = *(const bf16x8*)&Bs_lo[(wn * 64 + i * 16 + fr) * 32 + kh];
    }
#pragma unroll
    for (int i = 0; i < 4; i++)
#pragma unroll
      for (int j = 0; j < 4; j++) {
        acc[i][j] = __builtin_amdgcn_mfma_f32_16x16x32_bf16(
            ah[i], bh[j], acc[i][j], 0, 0, 0);
        acc[i][j] = __builtin_amdgcn_mfma_f32_16x16x32_bf16(
            al[i], bh[j], acc[i][j], 0, 0, 0);
        acc[i][j] = __builtin_amdgcn_mfma_f32_16x16x32_bf16(
            ah[i], bl[j], acc[i][j], 0, 0, 0);
      }
  }

  // C/D layout (m89-verified): col = lane&15, row = (lane>>4)*4 + reg
  int col = lane & 15;
  int r4 = (lane >> 4) * 4;
#pragma unroll
  for (int i = 0; i < 4; i++)
#pragma unroll
    for (int j = 0; j < 4; j++) {
      int nn = n0 + bnl + wn * 64 + j * 16 + col;
      if (nn < kV) {
#pragma unroll
        for (int reg = 0; reg < 4; reg++) {
          int mm = bm + wm * 64 + i * 16 + r4 + reg;
          C[(size_t)mm * kV + nn] = acc[i][j][reg];
        }
      }
    }
}

// ------------------------------------------------------------ attention ----
// Flash-style, no materialized scores. Block = 4 waves = 4 consecutive
// queries of one (b,h). Online softmax; K/V chunks of 64 staged in LDS.
__global__ __launch_bounds__(256)
void k_attn(const float* __restrict__ qkv, float* __restrict__ o) {
  __shared__ float Ks[64][65];   // +1 pad: scores phase reads Ks[lane][d]
  __shared__ float Vs[64][65];
  __shared__ float qs[4][64];
  __shared__ float ps[4][64];
  int wave = threadIdx.x >> 6, lane = threadIdx.x & 63;
  int b = blockIdx.z, h = blockIdx.y;
  int q = blockIdx.x * 4 + wave;
  const float* qkv_b = qkv + (size_t)b * kT * (3 * kD);
  qs[wave][lane] = qkv_b[(size_t)q * (3 * kD) + h * kHD + lane];
  float m = -INFINITY, l = 0.f, oacc = 0.f;
  int nch = (blockIdx.x * 4 + 3) / 64 + 1;  // same trip count for all waves
  for (int c = 0; c < nch; c++) {
    __syncthreads();
#pragma unroll
    for (int i = 0; i < 4; i++) {
      int f4 = threadIdx.x + i * 256;           // 0..1023 over 64x16 float4s
      int r = f4 >> 4, c4 = (f4 & 15) * 4;
      const float* kp = qkv_b + (size_t)(c * 64 + r) * (3 * kD) + kD + h * kHD + c4;
      const float* vp = kp + kD;
      float4 kv = *(const float4*)kp;
      float4 vv = *(const float4*)vp;
      Ks[r][c4 + 0] = kv.x; Ks[r][c4 + 1] = kv.y;
      Ks[r][c4 + 2] = kv.z; Ks[r][c4 + 3] = kv.w;
      Vs[r][c4 + 0] = vv.x; Vs[r][c4 + 1] = vv.y;
      Vs[r][c4 + 2] = vv.z; Vs[r][c4 + 3] = vv.w;
    }
    __syncthreads();
    // scores: lane owns key j = lane of this chunk
    float s = 0.f;
#pragma unroll
    for (int d = 0; d < 64; d++) s = fmaf(qs[wave][d], Ks[lane][d], s);
    s *= 0.125f;                                 // 1/sqrt(64)
    int jj = c * 64 + lane;
    if (jj > q) s = -INFINITY;                   // causal mask
    float smax = s;
#pragma unroll
    for (int off = 32; off >= 1; off >>= 1)
      smax = fmaxf(smax, __shfl_xor(smax, off, 64));
    float mnew = fmaxf(m, smax);
    float alpha = expf(m - mnew);                // m=-inf first time -> 0
    float p = expf(s - mnew);                    // masked -> 0
    float psum = p;
#pragma unroll
    for (int off = 32; off >= 1; off >>= 1) psum += __shfl_xor(psum, off, 64);
    l = l * alpha + psum;
    ps[wave][lane] = p;
    __syncthreads();
    // PV: lane owns output dim d = lane
    float pv = 0.f;
#pragma unroll
    for (int j = 0; j < 64; j++) pv = fmaf(ps[wave][j], Vs[j][lane], pv);
    oacc = oacc * alpha + pv;
    m = mnew;
  }
  o[(size_t)(b * kT + q) * kD + h * kHD + lane] = oacc / l;
}

// --------------------------------------------------------------- launch ----
extern "C" void kernel_launch(void* const* d_in, const int* in_sizes, int n_in,
                              void* d_out, int out_size, void* d_ws,
                              size_t ws_size, hipStream_t stream) {
  const int*   tok    = (const int*)d_in[0];
  const float* wte    = (const float*)d_in[1];
  const float* wpe    = (const float*)d_in[2];
  const float* ln1_w  = (const float*)d_in[3];
  const float* ln1_b  = (const float*)d_in[4];
  const float* attn_w = (const float*)d_in[5];
  const float* attn_b = (const float*)d_in[6];
  const float* proj_w = (const float*)d_in[7];
  const float* proj_b = (const float*)d_in[8];
  const float* ln2_w  = (const float*)d_in[9];
  const float* ln2_b  = (const float*)d_in[10];
  const float* fc_w   = (const float*)d_in[11];
  const float* fc_b   = (const float*)d_in[12];
  const float* fc2_w  = (const float*)d_in[13];
  const float* fc2_b  = (const float*)d_in[14];
  const float* lnf_w  = (const float*)d_in[15];
  const float* lnf_b  = (const float*)d_in[16];
  const float* head_w = (const float*)d_in[17];
  float* out = (float*)d_out;

  float* X   = (float*)d_ws;
  float* Hb  = X + (size_t)kM * kD;
  float* QKV = Hb + (size_t)kM * kD;
  float* U   = QKV + (size_t)kM * 3 * kD;
  unsigned short* Ahi  = (unsigned short*)(U + (size_t)kM * kF);
  unsigned short* Alo  = Ahi + (size_t)kM * kD;
  unsigned short* Wbuf = Alo + (size_t)kM * kD;

  size_t used = (size_t)((char*)Wbuf - (char*)d_ws);
  size_t avail = (ws_size > used) ? ws_size - used : 0;
  const size_t per_row = (size_t)kD * 2 * 2;    // hi+lo bf16 per W row
  int rc = (int)((avail / per_row) & ~(size_t)127);  // chunk rows, mult of 128
  if (rc > kVpad) rc = kVpad;

  k_embed<<<(kM * kD / 4) / 256, 256, 0, stream>>>(tok, wte, wpe, X);

  for (int l = 0; l < kL; l++) {
    k_ln<<<kM / 4, 256, 0, stream>>>(X, ln1_w + l * kD, ln1_b + l * kD, Hb);
    k_gemm<0><<<dim3(3 * kD / 64, kM / 64), 256, 0, stream>>>(
        Hb, attn_w + (size_t)l * kD * 3 * kD, attn_b + (size_t)l * 3 * kD,
        nullptr, QKV, kM, 3 * kD, kD);
    k_attn<<<dim3(kT / 4, kH, kB), 256, 0, stream>>>(QKV, Hb);
    k_gemm<0><<<dim3(kD / 64, kM / 64), 256, 0, stream>>>(
        Hb, proj_w + (size_t)l * kD * kD, proj_b + (size_t)l * kD,
        X, X, kM, kD, kD);
    k_ln<<<kM / 4, 256, 0, stream>>>(X, ln2_w + l * kD, ln2_b + l * kD, Hb);
    k_gemm<1><<<dim3(kF / 64, kM / 64), 256, 0, stream>>>(
        Hb, fc_w + (size_t)l * kD * kF, fc_b + (size_t)l * kF,
        nullptr, U, kM, kF, kD);
    k_gemm<0><<<dim3(kD / 64, kM / 64), 256, 0, stream>>>(
        U, fc2_w + (size_t)l * kF * kD, fc2_b + (size_t)l * kD,
        X, X, kM, kD, kF);
  }

  k_ln<<<kM / 4, 256, 0, stream>>>(X, lnf_w, lnf_b, Hb);

  if (rc >= 128) {
    // split-bf16 MFMA head: cast A once, then per-W-chunk cast + GEMM
    k_castA<<<(kM * kD / 4) / 256, 256, 0, stream>>>(Hb, Ahi, Alo);
    unsigned short* Whi = Wbuf;
    unsigned short* Wlo = Wbuf + (size_t)rc * kD;
    for (int n0 = 0; n0 < kVpad; n0 += rc) {
      int cur = (kVpad - n0 < rc) ? (kVpad - n0) : rc;
      k_castW<<<(cur * (kD / 4)) / 256, 256, 0, stream>>>(head_w, Whi, Wlo, n0);
      k_head_mfma<<<dim3(kM / 128, cur / 128), 256, 0, stream>>>(
          Ahi, Alo, Whi, Wlo, out, n0);
    }
  } else {
    // workspace too small for bf16 W chunk: fp32 fallback
    k_gemm_bt<<<dim3((kV + 63) / 64, kM / 64), 256, 0, stream>>>(
        Hb, head_w, out, kM, kV, kD);
  }
}